// Round 1
// baseline (219.608 us; speedup 1.0000x reference)
//
#include <hip/hip_runtime.h>
#include <cstdint>
#include <cstddef>

#define B_N   16
#define G_N   128
#define FD_N  8192
#define KSPLIT 16
#define KC    512        // FD_N / KSPLIT
#define BK2   32
#define NITER 16         // KC / BK2

typedef unsigned short u16;
typedef u16  u16x8 __attribute__((ext_vector_type(8)));
typedef __bf16 bf16x8 __attribute__((ext_vector_type(8)));
typedef float f32x16 __attribute__((ext_vector_type(16)));

// ---- ws layout (float offsets). Everything written before read; NO zero-init needed.
#define QSUM_P   0        // [kch][b][row] 16*16*128
#define QSSQ_P   32768
#define KSUM_P   65536
#define KSSQ_P   98304
#define NSSQ_P   131072
#define SM_ROW   163840   // [b][row]
#define CE_ROW   165888
#define S_OFF    167936   // [b][128][128] fp32 normalized S
#define PART_OFF_F 430080 // u16 region: [512 blk][128][128] bf16 partials (16.8 MB)

__device__ __forceinline__ u16 f2bf(float f) {
    uint32_t u = __float_as_uint(f);
    u += 0x7FFFu + ((u >> 16) & 1u);      // RNE
    return (u16)(u >> 16);
}

// async global->LDS, 16B per lane. LDS dest must be WAVE-UNIFORM base; HW writes base + lane*16.
__device__ __forceinline__ void load_lds16(const float* g, float* l) {
    __builtin_amdgcn_global_load_lds(
        (__attribute__((address_space(1))) void*)(g),
        (__attribute__((address_space(3))) void*)(l),
        16, 0, 0);
}

#define WAITV4() asm volatile("s_waitcnt vmcnt(4)" ::: "memory")
#define WAITV0() asm volatile("s_waitcnt vmcnt(0)" ::: "memory")

// ================= K1: bf16 GEMM 128x128 tile (A=q, B=k|n) ===================================
// grid = 16*2*16 = 512 blocks x 512 thr (2 blocks/CU).
// fp32 staged straight to LDS via global_load_lds (width 16), double-buffered, counted vmcnt(4)
// so the next tile's DMA stays in flight across both barriers. Source addresses carry the
// inverse XOR-swizzle (16B slot ^ (row&7)); LDS dest is linear; ds_reads apply the same XOR
// (residual 4-way conflict). Stats + f2bf happen at fragment-read time:
//   wn==0 waves own A-row stats, wm==0 waves own B-row stats (each element exactly once).
__global__ __launch_bounds__(512, 4)
void k_gemm(const float* __restrict__ q, const float* __restrict__ kM,
            const float* __restrict__ nM, float* __restrict__ ws)
{
    __shared__ __align__(16) float sA[2][G_N * BK2];   // 2 x 16 KB
    __shared__ __align__(16) float sB[2][G_N * BK2];   // 2 x 16 KB  (64 KB total)

    const int tid = threadIdx.x;
    const int blk = blockIdx.x;
    const int b    = blk >> 5;
    const int rem  = blk & 31;
    const int half = rem >> 4;        // 0: B=k, 1: B=n
    const int kch  = rem & 15;

    const int lane  = tid & 63;
    const int wv    = tid >> 6;       // 8 waves
    const int wm    = wv >> 2;        // 0..1 -> 64-row block
    const int wn    = wv & 3;         // 0..3 -> 32-col block
    const int khalf = lane >> 5;
    const int lrow  = lane & 31;
    const int rA0 = wm*64 + lrow;
    const int rB0 = wn*32 + lrow;
    const bool statA = (wn == 0);
    const bool statB = (wm == 0);

    const size_t mat_off = (size_t)b * (G_N * FD_N) + (size_t)kch * KC;
    const float* Ap = q + mat_off;
    const float* Bp = (half ? nM : kM) + mat_off;

    // staging geometry: wave w, instr j covers rows w*16+j*8 .. +8, 8x16B slots per row.
    // lane -> (row = base + lane>>3, slot t = lane&7); global col-slot = t ^ (row&7).
    const int r0s = wv*16 + (lane >> 3);
    const int r1s = r0s + 8;
    const size_t goff0 = (size_t)r0s * FD_N + (size_t)(((lane & 7) ^ (r0s & 7)) << 2);
    const size_t goff1 = (size_t)r1s * FD_N + (size_t)(((lane & 7) ^ (r1s & 7)) << 2);
    const int lds0 = wv * 512;        // float offset of wave's first 1KB chunk (wave-uniform)
    const int lds1 = wv * 512 + 256;

#define STAGE(ST, T) do {                                                     \
        const size_t tof_ = (size_t)((T) * BK2);                              \
        load_lds16(Ap + goff0 + tof_, &sA[ST][lds0]);                         \
        load_lds16(Bp + goff0 + tof_, &sB[ST][lds0]);                         \
        load_lds16(Ap + goff1 + tof_, &sA[ST][lds1]);                         \
        load_lds16(Bp + goff1 + tof_, &sB[ST][lds1]);                         \
    } while (0)

    // fragment read: logical floats [CH*8, CH*8+8) of row R = swizzled slots (CH*2)^x, (CH*2+1)^x
#define LOADCVT(SP, R, CH, FR, EN, SS, QQ) do {                               \
        const int x_ = (R) & 7;                                               \
        const float* rp_ = (SP) + (R) * BK2;                                  \
        float4 lo_ = *(const float4*)(rp_ + ((((CH)*2    ) ^ x_) << 2));      \
        float4 hi_ = *(const float4*)(rp_ + ((((CH)*2 + 1) ^ x_) << 2));      \
        if (EN) {                                                             \
            SS += (lo_.x + lo_.y) + (lo_.z + lo_.w)                           \
                + (hi_.x + hi_.y) + (hi_.z + hi_.w);                          \
            QQ += lo_.x*lo_.x + lo_.y*lo_.y + lo_.z*lo_.z + lo_.w*lo_.w       \
                + hi_.x*hi_.x + hi_.y*hi_.y + hi_.z*hi_.z + hi_.w*hi_.w;      \
        }                                                                     \
        u16x8 h_;                                                             \
        h_[0]=f2bf(lo_.x); h_[1]=f2bf(lo_.y); h_[2]=f2bf(lo_.z); h_[3]=f2bf(lo_.w); \
        h_[4]=f2bf(hi_.x); h_[5]=f2bf(hi_.y); h_[6]=f2bf(hi_.z); h_[7]=f2bf(hi_.w); \
        FR = __builtin_bit_cast(bf16x8, h_);                                  \
    } while (0)

#define COMPUTE_PHASE(ST) do {                                                \
        const float* sAp_ = &sA[ST][0];                                       \
        const float* sBp_ = &sB[ST][0];                                       \
        _Pragma("unroll")                                                     \
        for (int s = 0; s < 2; ++s) {                                         \
            const int ch = s*2 + khalf;                                       \
            bf16x8 af0, af1, bfv;                                             \
            LOADCVT(sAp_, rA0,      ch, af0, statA, aS0, aQ0);                \
            LOADCVT(sAp_, rA0 + 32, ch, af1, statA, aS1, aQ1);                \
            LOADCVT(sBp_, rB0,      ch, bfv, statB, bS0, bQ0);                \
            acc[0] = __builtin_amdgcn_mfma_f32_32x32x16_bf16(af0, bfv, acc[0], 0, 0, 0); \
            acc[1] = __builtin_amdgcn_mfma_f32_32x32x16_bf16(af1, bfv, acc[1], 0, 0, 0); \
        }                                                                     \
    } while (0)

    float aS0 = 0.f, aQ0 = 0.f, aS1 = 0.f, aQ1 = 0.f, bS0 = 0.f, bQ0 = 0.f;

    f32x16 acc[2];
    #pragma unroll
    for (int mb = 0; mb < 2; ++mb)
      #pragma unroll
      for (int e = 0; e < 16; ++e) acc[mb][e] = 0.f;

    // prologue: both buffers in flight (8 outstanding DMA loads per wave)
    STAGE(0, 0);
    STAGE(1, 1);

    // steady state: WAITV4 drains the oldest 4 (this buffer's tile), keeps the other
    // buffer's 4 in flight across the barriers.
    for (int t = 0; t < 14; t += 2) {
        WAITV4();
        __builtin_amdgcn_s_barrier();
        COMPUTE_PHASE(0);
        __builtin_amdgcn_s_barrier();
        STAGE(0, t + 2);

        WAITV4();
        __builtin_amdgcn_s_barrier();
        COMPUTE_PHASE(1);
        __builtin_amdgcn_s_barrier();
        STAGE(1, t + 3);
    }
    // tile 14
    WAITV4();
    __builtin_amdgcn_s_barrier();
    COMPUTE_PHASE(0);
    __builtin_amdgcn_s_barrier();
    // tile 15 (last: drain)
    WAITV0();
    __builtin_amdgcn_s_barrier();
    COMPUTE_PHASE(1);

    // bf16 partial C: C/D layout col=lane&31, row=(reg&3)+8*(reg>>2)+4*(lane>>5)
    u16* part = (u16*)(ws + PART_OFF_F) + ((size_t)blk << 14);
    #pragma unroll
    for (int mb = 0; mb < 2; ++mb) {
        int col = wn*32 + lrow;
        int rbase = wm*64 + mb*32 + 4*khalf;
        #pragma unroll
        for (int reg = 0; reg < 16; ++reg) {
            int row = rbase + (reg & 3) + 8*(reg >> 2);
            part[row*G_N + col] = f2bf(acc[mb][reg]);
        }
    }

    // row stats: lane l holds chunks {khalf, khalf+2} per tile; pair with l^32 for the full row.
    if (statA) {
        aS0 += __shfl_xor(aS0, 32, 64); aQ0 += __shfl_xor(aQ0, 32, 64);
        aS1 += __shfl_xor(aS1, 32, 64); aQ1 += __shfl_xor(aQ1, 32, 64);
        if (half == 0 && khalf == 0) {
            int o = kch*2048 + b*G_N + wm*64 + lrow;
            ws[QSUM_P + o]      = aS0; ws[QSSQ_P + o]      = aQ0;
            ws[QSUM_P + o + 32] = aS1; ws[QSSQ_P + o + 32] = aQ1;
        }
    }
    if (statB) {
        bS0 += __shfl_xor(bS0, 32, 64); bQ0 += __shfl_xor(bQ0, 32, 64);
        if (khalf == 0) {
            int o = kch*2048 + b*G_N + wn*32 + lrow;
            if (half == 0) { ws[KSUM_P + o] = bS0; ws[KSSQ_P + o] = bQ0; }
            else           { ws[NSSQ_P + o] = bQ0; }
        }
    }
#undef STAGE
#undef LOADCVT
#undef COMPUTE_PHASE
}

// ================= K2: reduce chunks + normalize + write S / sm-row / CE-expsum-row ==========
// grid = 16b * 2half * 8rowgroups = 256 blocks x 256 thr. Also zeroes out[0] for K3's atomics.
__global__ __launch_bounds__(256)
void k_red2(float* __restrict__ ws, float* __restrict__ out)
{
    const int blk  = blockIdx.x;
    const int b    = blk >> 4;
    const int half = (blk >> 3) & 1;
    const int rg   = blk & 7;
    const int t    = threadIdx.x;
    const int lr   = t >> 4;            // 0..15
    const int i    = rg*16 + lr;
    const int c8   = t & 15;            // 8 cols each
    __shared__ float nrm[128];          // 1/||k_j|| or 1/||n_j||
    __shared__ float invq_s[16];

    if (blk == 0 && t == 0) out[0] = 0.f;

    if (t < 128) {
        float ss = 0.f;
        const float* p = ws + (half ? NSSQ_P : KSSQ_P) + b*G_N + t;
        #pragma unroll
        for (int kc2 = 0; kc2 < KSPLIT; ++kc2) ss += p[kc2*2048];
        nrm[t] = 1.f / fmaxf(sqrtf(ss), 1e-12f);
    } else if (t < 144) {
        float ss = 0.f;
        const float* p = ws + QSSQ_P + b*G_N + rg*16 + (t - 128);
        #pragma unroll
        for (int kc2 = 0; kc2 < KSPLIT; ++kc2) ss += p[kc2*2048];
        invq_s[t-128] = 1.f / fmaxf(sqrtf(ss), 1e-12f);
    }
    __syncthreads();

    const u16* part = (const u16*)(ws + PART_OFF_F);
    float s[8] = {0,0,0,0,0,0,0,0};
    #pragma unroll
    for (int kc2 = 0; kc2 < KSPLIT; ++kc2) {
        size_t idx = ((size_t)(b*32 + half*16 + kc2) << 14) + i*G_N + c8*8;
        u16x8 h = *(const u16x8*)(part + idx);
        #pragma unroll
        for (int e = 0; e < 8; ++e)
            s[e] += __uint_as_float(((uint32_t)h[e]) << 16);
    }
    const float iq = invq_s[lr];
    if (half == 0) {
        float smacc = 0.f;
        float S8[8];
        #pragma unroll
        for (int e = 0; e < 8; ++e) {
            int j = c8*8 + e;
            S8[e] = s[e] * iq * nrm[j];
            float d = S8[e] - (j == i ? 1.f : 0.f);
            smacc += d*d;
        }
        float* Sp = ws + S_OFF + (size_t)b*16384 + i*G_N + c8*8;
        float4 w0 = {S8[0],S8[1],S8[2],S8[3]};
        float4 w1 = {S8[4],S8[5],S8[6],S8[7]};
        *(float4*)Sp = w0; *(float4*)(Sp+4) = w1;
        #pragma unroll
        for (int m = 8; m >= 1; m >>= 1) smacc += __shfl_xor(smacc, m, 64);
        if (c8 == 0) ws[SM_ROW + b*G_N + i] = smacc;
    } else {
        float eacc = 0.f;
        #pragma unroll
        for (int e = 0; e < 8; ++e)
            eacc += __expf(5.f * s[e] * iq * nrm[c8*8+e]);
        #pragma unroll
        for (int m = 8; m >= 1; m >>= 1) eacc += __shfl_xor(eacc, m, 64);
        if (c8 == 0) ws[CE_ROW + b*G_N + i] = eacc;
    }
}

// ================= K3: tri/cyc/ce + weighted combine, atomic into out =================
// grid = 16b * 8rowgroups = 128 blocks x 256 thr. out[0] zeroed by K2 (stream-ordered).
__global__ __launch_bounds__(256)
void k_epi(float* __restrict__ ws, float* __restrict__ out)
{
    const int blk = blockIdx.x;
    const int b   = blk >> 3;
    const int i0  = (blk & 7) * 16;
    const int t   = threadIdx.x;
    __shared__ float sqv[128], skv[128], ddq[128], ddk[128];
    __shared__ float rbuf[4];
    const float c0 = (float)FD_N * 1e-6f * 1e-6f;

    const float* S = ws + S_OFF + (size_t)b * 16384;
    if (t < 128) {
        float qs=0, qq=0, ks=0, kq=0;
        #pragma unroll
        for (int kc2 = 0; kc2 < KSPLIT; ++kc2) {
            int o = kc2*2048 + b*G_N + t;
            qs += ws[QSUM_P + o]; qq += ws[QSSQ_P + o];
            ks += ws[KSUM_P + o]; kq += ws[KSSQ_P + o];
        }
        float iq = 1.f/fmaxf(sqrtf(qq),1e-12f);
        float ik = 1.f/fmaxf(sqrtf(kq),1e-12f);
        float sq = qs*iq, sk = ks*ik;
        sqv[t]=sq; skv[t]=sk;
        float Stt = S[t*G_N + t];
        ddq[t] = sqrtf(fmaxf(2.f - 2.f*Stt + 2e-6f*(sq-sk) + c0, 0.f));
        ddk[t] = sqrtf(fmaxf(2.f - 2.f*Stt + 2e-6f*(sk-sq) + c0, 0.f));
    }
    __syncthreads();

    float tri=0.f, cyc=0.f, ce=0.f, sm=0.f;
    #pragma unroll
    for (int p = 0; p < 8; ++p) {
        int idx = p*256 + t;
        int i = i0 + (idx >> 7), j = idx & 127;
        if (i != j) {
            float S_ij = S[i*G_N + j];
            float dqk = sqrtf(fmaxf(2.f - 2.f*S_ij + 2e-6f*(sqv[i]-skv[j]) + c0, 0.f));
            tri += fmaxf(ddq[i] - dqk + 1.f, 0.f);
            float dkq = sqrtf(fmaxf(2.f - 2.f*S_ij + 2e-6f*(skv[j]-sqv[i]) + c0, 0.f));
            tri += fmaxf(ddk[j] - dkq + 1.f, 0.f);
            cyc += fabsf(S_ij - S[j*G_N + i]);
        }
    }
    if (t < 16) {
        int r = i0 + t;
        float lp = 5.f * S[r*G_N + r];
        ce = __logf(ws[CE_ROW + b*G_N + r] + __expf(lp)) - lp;
        sm = ws[SM_ROW + b*G_N + r];
    }
    float contrib = sm * (1.f/16384.f) + cyc * (1.f/16256.f) + ce * (1.f/16384.f)
                  + (float)(B_N - b) * tri * (1.f/32512.f);
    #pragma unroll
    for (int m = 32; m >= 1; m >>= 1) contrib += __shfl_xor(contrib, m, 64);
    if ((t & 63) == 0) rbuf[t >> 6] = contrib;
    __syncthreads();
    if (t == 0) atomicAdd(out, rbuf[0] + rbuf[1] + rbuf[2] + rbuf[3]);
}

extern "C" void kernel_launch(void* const* d_in, const int* in_sizes, int n_in,
                              void* d_out, int out_size, void* d_ws, size_t ws_size,
                              hipStream_t stream)
{
    const float* q  = (const float*)d_in[0];
    const float* kM = (const float*)d_in[1];
    const float* nM = (const float*)d_in[2];
    float* ws  = (float*)d_ws;
    float* out = (float*)d_out;

    k_gemm<<<B_N * 2 * KSPLIT, 512, 0, stream>>>(q, kM, nM, ws);
    k_red2<<<256, 256, 0, stream>>>(ws, out);
    k_epi<<<128, 256, 0, stream>>>(ws, out);
}